// Round 4
// baseline (1826.424 us; speedup 1.0000x reference)
//
#include <hip/hip_runtime.h>
#include <hip/hip_bf16.h>
#include <math.h>

#define SEQ   2048
#define HID   2048
#define NHEAD 16
#define DHEAD 128
#define NB    32
#define BATCH 2
#define MROWS (BATCH * SEQ)   // 4096
#define NQKV  (3 * HID)       // 6144

typedef _Float16 f16;
typedef _Float16 f16x8 __attribute__((ext_vector_type(8)));
typedef _Float16 f16x4 __attribute__((ext_vector_type(4)));
typedef float f32x4 __attribute__((ext_vector_type(4)));

// ---------------------------------------------------------------------------
// Mask canonicalization — element-size agnostic (bool byte / int32 / int64).
// Row 0 is an all-True global row: bool => byte1 nonzero; int32 LE => bytes
// 1..3 zero, byte4 (elem 1) nonzero; int64 => bytes 1..7 zero, byte8 nonzero.
// ---------------------------------------------------------------------------
__global__ __launch_bounds__(256) void detect_kernel(
    const unsigned char* __restrict__ mask, int* __restrict__ flag,
    int* __restrict__ act) {
  const int tid = threadIdx.x + blockIdx.x * blockDim.x;
  if (tid < NB * NB) act[tid] = 0;
  if (tid == 0) {
    int e;
    if (mask[1] | mask[2] | mask[3]) e = 1;
    else if (mask[4]) e = 4;
    else e = 8;
    flag[0] = e;
  }
}

__device__ inline int mask_at(const unsigned char* m, size_t idx, int esize) {
  if (esize == 1) return m[idx];
  if (esize == 4) return ((const int*)m)[idx] != 0;
  return ((const long long*)m)[idx] != 0;
}

// 64 threads handle 2 query rows; thread = (row_in_pair, kblock).
__global__ __launch_bounds__(64) void masknorm_kernel(
    const unsigned char* __restrict__ mask, const int* __restrict__ flag,
    unsigned long long* __restrict__ colmask, int* __restrict__ act) {
  const int row = blockIdx.x * 2 + (threadIdx.x >> 5);
  const int kb = threadIdx.x & 31;
  const int esize = flag[0];
  unsigned long long bm = 0ull;
  const size_t base = (size_t)row * SEQ + (size_t)kb * 64;
#pragma unroll 8
  for (int c = 0; c < 64; c++)
    if (mask_at(mask, base + c, esize)) bm |= (1ull << c);
  colmask[(size_t)row * NB + kb] = bm;
  if (bm) atomicOr(&act[(row >> 6) * NB + kb], 1);
}

// ---------------------------------------------------------------------------
// Weight transpose+convert: W[K][N] fp32 -> WT[N][K] f16.
// z = 0,1,2,3 -> Wq,Wk,Wv,Wo, written at z*HID*HID.
// ---------------------------------------------------------------------------
__global__ __launch_bounds__(256) void wtrans_kernel(
    const float* __restrict__ W0, const float* __restrict__ W1,
    const float* __restrict__ W2, const float* __restrict__ W3,
    f16* __restrict__ WT) {
  const float* W = (blockIdx.z == 0) ? W0
                 : (blockIdx.z == 1) ? W1
                 : (blockIdx.z == 2) ? W2 : W3;
  f16* out = WT + (size_t)blockIdx.z * HID * HID;
  __shared__ float T[64][65];
  const int t = threadIdx.x;
  const int k0 = blockIdx.y * 64, n0 = blockIdx.x * 64;
#pragma unroll
  for (int i = 0; i < 4; i++) {
    int f = t + i * 256;
    int kr = f >> 4, nc = (f & 15) << 2;
    float4 v = *(const float4*)(W + (size_t)(k0 + kr) * HID + n0 + nc);
    T[kr][nc] = v.x; T[kr][nc + 1] = v.y; T[kr][nc + 2] = v.z; T[kr][nc + 3] = v.w;
  }
  __syncthreads();
#pragma unroll
  for (int i = 0; i < 4; i++) {
    int f = t + i * 256;
    int nr = f >> 4, kc = (f & 15) << 2;
    f16x4 ov = {(f16)T[kc][nr], (f16)T[kc + 1][nr], (f16)T[kc + 2][nr],
                (f16)T[kc + 3][nr]};
    *(f16x4*)(out + (size_t)(n0 + nr) * HID + k0 + kc) = ov;
  }
}

// X fp32 -> f16, 8 elems/thread.
__global__ __launch_bounds__(256) void xconv_kernel(const float* __restrict__ X,
                                                    f16* __restrict__ Xh) {
  const size_t i = ((size_t)blockIdx.x * 256 + threadIdx.x) * 8;
  float4 a = *(const float4*)(X + i);
  float4 b = *(const float4*)(X + i + 4);
  f16x8 h = {(f16)a.x, (f16)a.y, (f16)a.z, (f16)a.w,
             (f16)b.x, (f16)b.y, (f16)b.z, (f16)b.w};
  *(f16x8*)(Xh + i) = h;
}

// ---------------------------------------------------------------------------
// fp16-MFMA GEMM: C[M][N] = A[M][K] @ BT[N][K]^T, A/BT f16, acc fp32.
// 256 thr = 4 waves (2x2), wave tile 64x64 = 4x4 frags 16x16, BK=32.
// LDS rows padded to 40 f16 (80 B): frag ds_read_b128 -> 2-way alias (free).
// C/D: col=lane&15, row=(lane>>4)*4+j (m91-verified mapping).
// ---------------------------------------------------------------------------
template <bool C_F16>
__global__ __launch_bounds__(256) void hgemm_kernel(
    const f16* __restrict__ A, const f16* __restrict__ BT,
    void* __restrict__ Cp, int M, int N, int K) {
  __shared__ f16 Ah[128][40];
  __shared__ f16 Bh[128][40];
  const int tid = threadIdx.x;
  const int m0 = blockIdx.y * 128, n0 = blockIdx.x * 128;
  const int lane = tid & 63, wid = tid >> 6;
  const int wr = (wid >> 1) * 64, wc = (wid & 1) * 64;
  const int fr = lane & 15;
  const int k8 = (lane >> 4) * 8;

  f32x4 acc[4][4] = {};

  for (int kk = 0; kk < K; kk += 32) {
    __syncthreads();
#pragma unroll
    for (int i = 0; i < 2; i++) {
      int f = tid + i * 256;          // 0..511
      int row = f >> 2;               // 0..127
      int kc = (f & 3) << 3;          // 0,8,16,24
      *(f16x8*)(&Ah[row][kc]) =
          *(const f16x8*)(A + (size_t)(m0 + row) * K + kk + kc);
      *(f16x8*)(&Bh[row][kc]) =
          *(const f16x8*)(BT + (size_t)(n0 + row) * K + kk + kc);
    }
    __syncthreads();

    f16x8 af[4], bf[4];
#pragma unroll
    for (int m = 0; m < 4; m++)
      af[m] = *(const f16x8*)(&Ah[wr + m * 16 + fr][k8]);
#pragma unroll
    for (int n = 0; n < 4; n++)
      bf[n] = *(const f16x8*)(&Bh[wc + n * 16 + fr][k8]);
#pragma unroll
    for (int m = 0; m < 4; m++)
#pragma unroll
      for (int n = 0; n < 4; n++)
        acc[m][n] = __builtin_amdgcn_mfma_f32_16x16x32_f16(af[m], bf[n],
                                                           acc[m][n], 0, 0, 0);
  }

  const int crow = (lane >> 4) * 4;
#pragma unroll
  for (int m = 0; m < 4; m++)
#pragma unroll
    for (int n = 0; n < 4; n++) {
      int gr = m0 + wr + m * 16 + crow;
      int gc = n0 + wc + n * 16 + fr;
#pragma unroll
      for (int j = 0; j < 4; j++) {
        if (C_F16)
          ((f16*)Cp)[(size_t)(gr + j) * N + gc] = (f16)acc[m][n][j];
        else
          ((float*)Cp)[(size_t)(gr + j) * N + gc] = acc[m][n][j];
      }
    }
}

// ---------------------------------------------------------------------------
// Fused block-sparse attention (flash-style): f16 Q/K/V (row stride `ldq`),
// fp32 compute, f16 AO out.  Grid (qblock=32, head=16, batch=2); 256 thr.
// Thread t: row r = t>>2 (0..63), d-quarter q4 = t&3 (32 dims, rotated).
// ---------------------------------------------------------------------------
__global__ __launch_bounds__(256) void attn_kernel(
    const f16* __restrict__ Q, const f16* __restrict__ K,
    const f16* __restrict__ V, const unsigned long long* __restrict__ colmask,
    const int* __restrict__ act, f16* __restrict__ AO, int ldq) {
  const int qi = blockIdx.x, h = blockIdx.y, b = blockIdx.z;
  const int tid = threadIdx.x;
  const int r = tid >> 2;
  const int q4 = tid & 3;
  const float SCALE = 0.08838834764831845f;  // 1/sqrt(128)

  __shared__ float Ks[64 * 128];
  __shared__ float Vs[64 * 128];

  int doff[8];
#pragma unroll
  for (int ii = 0; ii < 8; ii++)
    doff[ii] = q4 * 32 + (((ii + q4 * 2) & 7) << 2);

  const f16* Qp = Q + (size_t)(b * SEQ + qi * 64 + r) * ldq + h * DHEAD;
  float qreg[32];
#pragma unroll
  for (int ii = 0; ii < 8; ii++) {
    f16x4 qv = *(const f16x4*)(Qp + doff[ii]);
    qreg[ii * 4 + 0] = (float)qv.x;
    qreg[ii * 4 + 1] = (float)qv.y;
    qreg[ii * 4 + 2] = (float)qv.z;
    qreg[ii * 4 + 3] = (float)qv.w;
  }

  float m = -3.0e38f, l = 0.f;
  float o[32];
#pragma unroll
  for (int i = 0; i < 32; i++) o[i] = 0.f;

  const unsigned long long* cmrow = colmask + (size_t)(qi * 64 + r) * NB;

  for (int kb = 0; kb < NB; kb++) {
    if (!act[qi * NB + kb]) continue;  // uniform across workgroup

    __syncthreads();
    {
      const f16* Kp = K + (size_t)(b * SEQ + kb * 64) * ldq + h * DHEAD;
      const f16* Vp = V + (size_t)(b * SEQ + kb * 64) * ldq + h * DHEAD;
#pragma unroll
      for (int i = 0; i < 4; i++) {
        int f = tid + i * 256;          // 1024 chunks of 8
        int row = f >> 4, c8 = (f & 15) << 3;
        f16x8 kv = *(const f16x8*)(Kp + (size_t)row * ldq + c8);
        f16x8 vv = *(const f16x8*)(Vp + (size_t)row * ldq + c8);
        float* kd = Ks + row * 128 + c8;
        float* vd = Vs + row * 128 + c8;
#pragma unroll
        for (int j = 0; j < 8; j++) {
          kd[j] = (float)kv[j];
          vd[j] = (float)vv[j];
        }
      }
    }
    __syncthreads();

    float s[64];
#pragma unroll
    for (int c = 0; c < 64; c++) {
      const float* kr = Ks + c * 128;
      float dot = 0.f;
#pragma unroll
      for (int ii = 0; ii < 8; ii++) {
        float4 kv = *(const float4*)(kr + doff[ii]);
        dot = fmaf(qreg[ii * 4 + 0], kv.x, dot);
        dot = fmaf(qreg[ii * 4 + 1], kv.y, dot);
        dot = fmaf(qreg[ii * 4 + 2], kv.z, dot);
        dot = fmaf(qreg[ii * 4 + 3], kv.w, dot);
      }
      s[c] = dot;
    }
#pragma unroll
    for (int c = 0; c < 64; c++) {
      s[c] += __shfl_xor(s[c], 1);
      s[c] += __shfl_xor(s[c], 2);
    }

    const unsigned long long cm = cmrow[kb];
    float bmax = -3.0e38f;
#pragma unroll
    for (int c = 0; c < 64; c++) {
      float sv = s[c] * SCALE;
      if (!((cm >> c) & 1ull)) sv = -3.0e38f;
      s[c] = sv;
      bmax = fmaxf(bmax, sv);
    }

    float mnew = fmaxf(m, bmax);
    float co = __expf(m - mnew);
    float psum = 0.f;
#pragma unroll
    for (int c = 0; c < 64; c++) {
      float p = __expf(s[c] - mnew);
      s[c] = p;
      psum += p;
    }
    l = l * co + psum;
    m = mnew;
#pragma unroll
    for (int i = 0; i < 32; i++) o[i] *= co;

#pragma unroll
    for (int c = 0; c < 64; c++) {
      const float* vr = Vs + c * 128;
#pragma unroll
      for (int ii = 0; ii < 8; ii++) {
        float4 vv = *(const float4*)(vr + doff[ii]);
        o[ii * 4 + 0] = fmaf(s[c], vv.x, o[ii * 4 + 0]);
        o[ii * 4 + 1] = fmaf(s[c], vv.y, o[ii * 4 + 1]);
        o[ii * 4 + 2] = fmaf(s[c], vv.z, o[ii * 4 + 2]);
        o[ii * 4 + 3] = fmaf(s[c], vv.w, o[ii * 4 + 3]);
      }
    }
  }

  const float inv = 1.0f / l;
  f16* Op = AO + (size_t)(b * SEQ + qi * 64 + r) * HID + h * DHEAD;
#pragma unroll
  for (int ii = 0; ii < 8; ii++) {
    f16x4 ov = {(f16)(o[ii * 4 + 0] * inv), (f16)(o[ii * 4 + 1] * inv),
                (f16)(o[ii * 4 + 2] * inv), (f16)(o[ii * 4 + 3] * inv)};
    *(f16x4*)(Op + doff[ii]) = ov;
  }
}

// ---------------------------------------------------------------------------
extern "C" void kernel_launch(void* const* d_in, const int* in_sizes, int n_in,
                              void* d_out, int out_size, void* d_ws,
                              size_t ws_size, hipStream_t stream) {
  const float* X  = (const float*)d_in[0];
  const float* Wq = (const float*)d_in[1];
  const float* Wk = (const float*)d_in[2];
  const float* Wv = (const float*)d_in[3];
  const float* Wo = (const float*)d_in[4];
  const unsigned char* mask = (const unsigned char*)d_in[5];
  float* out = (float*)d_out;

  // ws layout (~96.6 MB)
  f16* WT  = (f16*)d_ws;                               // 4*HID*HID f16 = 32MB
  f16* Xh  = WT + (size_t)4 * HID * HID;               // 16MB
  f16* QKV = Xh + (size_t)MROWS * HID;                 // M x 6144 f16 = 48MB? no: 4096*6144*2 = 48MB... (ws >= 128MB per round-1 run)
  f16* AOh = QKV + (size_t)MROWS * NQKV;               // 16MB
  unsigned long long* colmask =
      (unsigned long long*)(AOh + (size_t)MROWS * HID);
  int* act  = (int*)(colmask + (size_t)SEQ * NB);
  int* flag = act + NB * NB;

  detect_kernel<<<4, 256, 0, stream>>>(mask, flag, act);
  masknorm_kernel<<<SEQ / 2, 64, 0, stream>>>(mask, flag, colmask, act);
  wtrans_kernel<<<dim3(HID / 64, HID / 64, 4), 256, 0, stream>>>(Wq, Wk, Wv,
                                                                 Wo, WT);
  xconv_kernel<<<(MROWS * HID) / (256 * 8), 256, 0, stream>>>(X, Xh);

  // Fused QKV projection: C[M][6144] = Xh @ WT[0:3*HID][:]^T
  hgemm_kernel<true><<<dim3(NQKV / 128, MROWS / 128), 256, 0, stream>>>(
      Xh, WT, QKV, MROWS, NQKV, HID);

  attn_kernel<<<dim3(NB, NHEAD, BATCH), 256, 0, stream>>>(
      QKV, QKV + HID, QKV + 2 * HID, colmask, act, AOh, NQKV);

  hgemm_kernel<false><<<dim3(HID / 128, MROWS / 128), 256, 0, stream>>>(
      AOh, WT + (size_t)3 * HID * HID, out, MROWS, HID, HID);
}

// Round 5
// 692.918 us; speedup vs baseline: 2.6358x; 2.6358x over previous
//
#include <hip/hip_runtime.h>
#include <hip/hip_bf16.h>
#include <math.h>

#define SEQ   2048
#define HID   2048
#define NHEAD 16
#define DHEAD 128
#define NB    32
#define BATCH 2
#define MROWS (BATCH * SEQ)   // 4096
#define NQKV  (3 * HID)       // 6144

typedef _Float16 f16;
typedef _Float16 f16x8 __attribute__((ext_vector_type(8)));
typedef _Float16 f16x4 __attribute__((ext_vector_type(4)));
typedef float f32x4 __attribute__((ext_vector_type(4)));

// ---------------------------------------------------------------------------
// Mask canonicalization — element-size agnostic (bool byte / int32 / int64).
// ---------------------------------------------------------------------------
__global__ __launch_bounds__(256) void detect_kernel(
    const unsigned char* __restrict__ mask, int* __restrict__ flag,
    int* __restrict__ act) {
  const int tid = threadIdx.x + blockIdx.x * blockDim.x;
  if (tid < NB * NB) act[tid] = 0;
  if (tid == 0) {
    int e;
    if (mask[1] | mask[2] | mask[3]) e = 1;
    else if (mask[4]) e = 4;
    else e = 8;
    flag[0] = e;
  }
}

__device__ inline int mask_at(const unsigned char* m, size_t idx, int esize) {
  if (esize == 1) return m[idx];
  if (esize == 4) return ((const int*)m)[idx] != 0;
  return ((const long long*)m)[idx] != 0;
}

__global__ __launch_bounds__(64) void masknorm_kernel(
    const unsigned char* __restrict__ mask, const int* __restrict__ flag,
    unsigned long long* __restrict__ colmask, int* __restrict__ act) {
  const int row = blockIdx.x * 2 + (threadIdx.x >> 5);
  const int kb = threadIdx.x & 31;
  const int esize = flag[0];
  unsigned long long bm = 0ull;
  const size_t base = (size_t)row * SEQ + (size_t)kb * 64;
#pragma unroll 8
  for (int c = 0; c < 64; c++)
    if (mask_at(mask, base + c, esize)) bm |= (1ull << c);
  colmask[(size_t)row * NB + kb] = bm;
  if (bm) atomicOr(&act[(row >> 6) * NB + kb], 1);
}

// ---------------------------------------------------------------------------
// Weight transpose+convert: W[K][N] fp32 -> WT[N][K] f16.
// ---------------------------------------------------------------------------
__global__ __launch_bounds__(256) void wtrans_kernel(
    const float* __restrict__ W0, const float* __restrict__ W1,
    const float* __restrict__ W2, const float* __restrict__ W3,
    f16* __restrict__ WT) {
  const float* W = (blockIdx.z == 0) ? W0
                 : (blockIdx.z == 1) ? W1
                 : (blockIdx.z == 2) ? W2 : W3;
  f16* out = WT + (size_t)blockIdx.z * HID * HID;
  __shared__ float T[64][65];
  const int t = threadIdx.x;
  const int k0 = blockIdx.y * 64, n0 = blockIdx.x * 64;
#pragma unroll
  for (int i = 0; i < 4; i++) {
    int f = t + i * 256;
    int kr = f >> 4, nc = (f & 15) << 2;
    float4 v = *(const float4*)(W + (size_t)(k0 + kr) * HID + n0 + nc);
    T[kr][nc] = v.x; T[kr][nc + 1] = v.y; T[kr][nc + 2] = v.z; T[kr][nc + 3] = v.w;
  }
  __syncthreads();
#pragma unroll
  for (int i = 0; i < 4; i++) {
    int f = t + i * 256;
    int nr = f >> 4, kc = (f & 15) << 2;
    f16x4 ov = {(f16)T[kc][nr], (f16)T[kc + 1][nr], (f16)T[kc + 2][nr],
                (f16)T[kc + 3][nr]};
    *(f16x4*)(out + (size_t)(n0 + nr) * HID + k0 + kc) = ov;
  }
}

__global__ __launch_bounds__(256) void xconv_kernel(const float* __restrict__ X,
                                                    f16* __restrict__ Xh) {
  const size_t i = ((size_t)blockIdx.x * 256 + threadIdx.x) * 8;
  float4 a = *(const float4*)(X + i);
  float4 b = *(const float4*)(X + i + 4);
  f16x8 h = {(f16)a.x, (f16)a.y, (f16)a.z, (f16)a.w,
             (f16)b.x, (f16)b.y, (f16)b.z, (f16)b.w};
  *(f16x8*)(Xh + i) = h;
}

// ---------------------------------------------------------------------------
// fp16-MFMA GEMM: C[M][N] = A[M][K] @ BT[N][K]^T  (validated round 4)
// ---------------------------------------------------------------------------
template <bool C_F16>
__global__ __launch_bounds__(256) void hgemm_kernel(
    const f16* __restrict__ A, const f16* __restrict__ BT,
    void* __restrict__ Cp, int M, int N, int K) {
  __shared__ f16 Ah[128][40];
  __shared__ f16 Bh[128][40];
  const int tid = threadIdx.x;
  const int m0 = blockIdx.y * 128, n0 = blockIdx.x * 128;
  const int lane = tid & 63, wid = tid >> 6;
  const int wr = (wid >> 1) * 64, wc = (wid & 1) * 64;
  const int fr = lane & 15;
  const int k8 = (lane >> 4) * 8;

  f32x4 acc[4][4] = {};

  for (int kk = 0; kk < K; kk += 32) {
    __syncthreads();
#pragma unroll
    for (int i = 0; i < 2; i++) {
      int f = tid + i * 256;
      int row = f >> 2;
      int kc = (f & 3) << 3;
      *(f16x8*)(&Ah[row][kc]) =
          *(const f16x8*)(A + (size_t)(m0 + row) * K + kk + kc);
      *(f16x8*)(&Bh[row][kc]) =
          *(const f16x8*)(BT + (size_t)(n0 + row) * K + kk + kc);
    }
    __syncthreads();

    f16x8 af[4], bf[4];
#pragma unroll
    for (int m = 0; m < 4; m++)
      af[m] = *(const f16x8*)(&Ah[wr + m * 16 + fr][k8]);
#pragma unroll
    for (int n = 0; n < 4; n++)
      bf[n] = *(const f16x8*)(&Bh[wc + n * 16 + fr][k8]);
#pragma unroll
    for (int m = 0; m < 4; m++)
#pragma unroll
      for (int n = 0; n < 4; n++)
        acc[m][n] = __builtin_amdgcn_mfma_f32_16x16x32_f16(af[m], bf[n],
                                                           acc[m][n], 0, 0, 0);
  }

  const int crow = (lane >> 4) * 4;
#pragma unroll
  for (int m = 0; m < 4; m++)
#pragma unroll
    for (int n = 0; n < 4; n++) {
      int gr = m0 + wr + m * 16 + crow;
      int gc = n0 + wc + n * 16 + fr;
#pragma unroll
      for (int j = 0; j < 4; j++) {
        if (C_F16)
          ((f16*)Cp)[(size_t)(gr + j) * N + gc] = (f16)acc[m][n][j];
        else
          ((float*)Cp)[(size_t)(gr + j) * N + gc] = acc[m][n][j];
      }
    }
}

// ---------------------------------------------------------------------------
// MFMA block-sparse flash attention.
// Grid (qblock=32, head=16, batch=2), 256 thr = 4 waves; wave w owns q-rows
// [w*16, w*16+16).  QK^T: A=Q (regs), B=K (LDS row-major, pad 136).
// PV computed as O^T = V^T x P^T:  A=V^T (LDS, XOR-swizzled k, pad 72),
// B=P rows (LDS, pad 72).  All frag reads are ds_read_b128, <=2-way banks.
// S/P lane layout: row q=(l>>4)*4+j, col key=l&15 (+16t).
// O^T lane layout: col q=l&15, row d=(l>>4)*4+j (+16dt).
// co/l cross lane-layouts via per-wave LDS slots (waitcnt+sched_barrier).
// ---------------------------------------------------------------------------
__global__ __launch_bounds__(256) void attn_kernel(
    const f16* __restrict__ Q, const f16* __restrict__ K,
    const f16* __restrict__ V, const unsigned long long* __restrict__ colmask,
    const int* __restrict__ act, f16* __restrict__ AO, int ldq) {
  const int qi = blockIdx.x, h = blockIdx.y, b = blockIdx.z;
  const int tid = threadIdx.x;
  const int lane = tid & 63, w = tid >> 6;
  const int l15 = lane & 15, l4 = lane >> 4;
  const float SCALE = 0.08838834764831845f;

  __shared__ f16 Ks[64 * 136];     // 17408 B
  __shared__ f16 VTs[128 * 72];    // 18432 B, VT[d][k^swz(d)]
  __shared__ f16 Ps[4][16 * 72];   // 9216 B, per-wave P[q][k]
  __shared__ float Cs[4][16];
  __shared__ float Ls[4][16];

  // Q fragments (A-operand): row = w*16 + l15, 4 k-chunks of 32 d.
  const f16* Qp = Q + (size_t)(b * SEQ + qi * 64 + w * 16 + l15) * ldq + h * DHEAD;
  f16x8 qf[4];
#pragma unroll
  for (int kc = 0; kc < 4; kc++)
    qf[kc] = *(const f16x8*)(Qp + kc * 32 + l4 * 8);

  // colmask rows for the softmax-state layout: q = w*16 + l4*4 + j
  const unsigned long long* cmbase =
      colmask + (size_t)(qi * 64 + w * 16 + l4 * 4) * NB;

  float mrow[4], lrow[4];
#pragma unroll
  for (int j = 0; j < 4; j++) { mrow[j] = -3.0e38f; lrow[j] = 0.f; }
  f32x4 oacc[8] = {};  // O^T tiles: d = dt*16 + (l4*4+j), q = l15

  const int* actrow = act + qi * NB;

  for (int kb = 0; kb < NB; kb++) {
    if (!actrow[kb]) continue;  // uniform across workgroup
    __syncthreads();
    // ---- stage K row-major + V^T swizzled ----
    {
      const f16* Kp = K + (size_t)(b * SEQ + kb * 64) * ldq + h * DHEAD;
      const f16* Vp = V + (size_t)(b * SEQ + kb * 64) * ldq + h * DHEAD;
#pragma unroll
      for (int i = 0; i < 4; i++) {
        int f = tid + i * 256;
        int row = f >> 4, c8 = (f & 15) << 3;
        *(f16x8*)(&Ks[row * 136 + c8]) =
            *(const f16x8*)(Kp + (size_t)row * ldq + c8);
      }
#pragma unroll
      for (int i = 0; i < 4; i++) {
        int f = tid + i * 256;
        int row = f >> 4, c8 = (f & 15) << 3;   // key row, d base
        f16x8 v = *(const f16x8*)(Vp + (size_t)row * ldq + c8);
#pragma unroll
        for (int j = 0; j < 8; j++) {
          int d = c8 + j;
          VTs[d * 72 + (row ^ (((d >> 3) & 7) << 3))] = v[j];
        }
      }
    }
    __syncthreads();

    // ---- QK^T ----
    f32x4 sacc[4] = {};
#pragma unroll
    for (int t = 0; t < 4; t++)
#pragma unroll
      for (int kc = 0; kc < 4; kc++) {
        f16x8 kf =
            *(const f16x8*)(&Ks[(t * 16 + l15) * 136 + kc * 32 + l4 * 8]);
        sacc[t] =
            __builtin_amdgcn_mfma_f32_16x16x32_f16(qf[kc], kf, sacc[t], 0, 0, 0);
      }

    // ---- mask + online softmax (state rows q = w*16 + l4*4 + j) ----
    unsigned long long cm[4];
#pragma unroll
    for (int j = 0; j < 4; j++) cm[j] = cmbase[j * NB + kb];

    float bmax[4] = {-3.0e38f, -3.0e38f, -3.0e38f, -3.0e38f};
    float sc[4][4];
#pragma unroll
    for (int t = 0; t < 4; t++)
#pragma unroll
      for (int j = 0; j < 4; j++) {
        float sv = sacc[t][j] * SCALE;
        if (!((cm[j] >> (t * 16 + l15)) & 1ull)) sv = -3.0e38f;
        sc[t][j] = sv;
        bmax[j] = fmaxf(bmax[j], sv);
      }
#pragma unroll
    for (int j = 0; j < 4; j++) {
      bmax[j] = fmaxf(bmax[j], __shfl_xor(bmax[j], 1));
      bmax[j] = fmaxf(bmax[j], __shfl_xor(bmax[j], 2));
      bmax[j] = fmaxf(bmax[j], __shfl_xor(bmax[j], 4));
      bmax[j] = fmaxf(bmax[j], __shfl_xor(bmax[j], 8));
    }
    float co[4], psum[4] = {0.f, 0.f, 0.f, 0.f};
#pragma unroll
    for (int j = 0; j < 4; j++) {
      float mnew = fmaxf(mrow[j], bmax[j]);
      co[j] = __expf(mrow[j] - mnew);
      mrow[j] = mnew;
    }
#pragma unroll
    for (int t = 0; t < 4; t++)
#pragma unroll
      for (int j = 0; j < 4; j++) {
        float p = __expf(sc[t][j] - mrow[j]);
        psum[j] += p;
        Ps[w][(l4 * 4 + j) * 72 + t * 16 + l15] = (f16)p;
      }
#pragma unroll
    for (int j = 0; j < 4; j++) {
      psum[j] += __shfl_xor(psum[j], 1);
      psum[j] += __shfl_xor(psum[j], 2);
      psum[j] += __shfl_xor(psum[j], 4);
      psum[j] += __shfl_xor(psum[j], 8);
      lrow[j] = lrow[j] * co[j] + psum[j];
    }
    if (l15 == 0) {
#pragma unroll
      for (int j = 0; j < 4; j++) Cs[w][l4 * 4 + j] = co[j];
    }
    asm volatile("s_waitcnt lgkmcnt(0)" ::: "memory");
    __builtin_amdgcn_sched_barrier(0);

    // ---- rescale O^T by co(q = l15), then PV ----
    float cq = Cs[w][l15];
#pragma unroll
    for (int dt = 0; dt < 8; dt++)
#pragma unroll
      for (int j = 0; j < 4; j++) oacc[dt][j] *= cq;

    f16x8 pf[2];
#pragma unroll
    for (int kc = 0; kc < 2; kc++)
      pf[kc] = *(const f16x8*)(&Ps[w][l15 * 72 + kc * 32 + l4 * 8]);
#pragma unroll
    for (int dt = 0; dt < 8; dt++)
#pragma unroll
      for (int kc = 0; kc < 2; kc++) {
        int d = dt * 16 + l15;
        int k8 = (kc * 32 + l4 * 8) ^ (((d >> 3) & 7) << 3);
        f16x8 vf = *(const f16x8*)(&VTs[d * 72 + k8]);
        oacc[dt] =
            __builtin_amdgcn_mfma_f32_16x16x32_f16(vf, pf[kc], oacc[dt], 0, 0, 0);
      }
  }

  // ---- epilogue: broadcast l, write AO[q][d] ----
  if (l15 == 0) {
#pragma unroll
    for (int j = 0; j < 4; j++) Ls[w][l4 * 4 + j] = lrow[j];
  }
  asm volatile("s_waitcnt lgkmcnt(0)" ::: "memory");
  __builtin_amdgcn_sched_barrier(0);
  const float linv = 1.0f / Ls[w][l15];
  f16* Op = AO + (size_t)(b * SEQ + qi * 64 + w * 16 + l15) * HID + h * DHEAD;
#pragma unroll
  for (int dt = 0; dt < 8; dt++) {
    f16x4 ov = {(f16)(oacc[dt][0] * linv), (f16)(oacc[dt][1] * linv),
                (f16)(oacc[dt][2] * linv), (f16)(oacc[dt][3] * linv)};
    *(f16x4*)(Op + dt * 16 + l4 * 4) = ov;
  }
}

// ---------------------------------------------------------------------------
extern "C" void kernel_launch(void* const* d_in, const int* in_sizes, int n_in,
                              void* d_out, int out_size, void* d_ws,
                              size_t ws_size, hipStream_t stream) {
  const float* X  = (const float*)d_in[0];
  const float* Wq = (const float*)d_in[1];
  const float* Wk = (const float*)d_in[2];
  const float* Wv = (const float*)d_in[3];
  const float* Wo = (const float*)d_in[4];
  const unsigned char* mask = (const unsigned char*)d_in[5];
  float* out = (float*)d_out;

  // ws layout (~112.5 MB)
  f16* WT  = (f16*)d_ws;                               // 32 MB
  f16* Xh  = WT + (size_t)4 * HID * HID;               // 16 MB
  f16* QKV = Xh + (size_t)MROWS * HID;                 // 48 MB
  f16* AOh = QKV + (size_t)MROWS * NQKV;               // 16 MB
  unsigned long long* colmask =
      (unsigned long long*)(AOh + (size_t)MROWS * HID);
  int* act  = (int*)(colmask + (size_t)SEQ * NB);
  int* flag = act + NB * NB;

  detect_kernel<<<4, 256, 0, stream>>>(mask, flag, act);
  masknorm_kernel<<<SEQ / 2, 64, 0, stream>>>(mask, flag, colmask, act);
  wtrans_kernel<<<dim3(HID / 64, HID / 64, 4), 256, 0, stream>>>(Wq, Wk, Wv,
                                                                 Wo, WT);
  xconv_kernel<<<(MROWS * HID) / (256 * 8), 256, 0, stream>>>(X, Xh);

  hgemm_kernel<true><<<dim3(NQKV / 128, MROWS / 128), 256, 0, stream>>>(
      Xh, WT, QKV, MROWS, NQKV, HID);

  attn_kernel<<<dim3(NB, NHEAD, BATCH), 256, 0, stream>>>(
      QKV, QKV + HID, QKV + 2 * HID, colmask, act, AOh, NQKV);

  hgemm_kernel<false><<<dim3(HID / 128, MROWS / 128), 256, 0, stream>>>(
      AOh, WT + (size_t)3 * HID * HID, out, MROWS, HID, HID);
}

// Round 8
// 480.172 us; speedup vs baseline: 3.8037x; 1.4431x over previous
//
#include <hip/hip_runtime.h>
#include <hip/hip_bf16.h>
#include <math.h>

#define SEQ   2048
#define HID   2048
#define NHEAD 16
#define DHEAD 128
#define NB    32
#define BATCH 2
#define MROWS (BATCH * SEQ)   // 4096
#define NQKV  (3 * HID)       // 6144

typedef _Float16 f16;
typedef _Float16 f16x8 __attribute__((ext_vector_type(8)));
typedef _Float16 f16x4 __attribute__((ext_vector_type(4)));
typedef float f32x4 __attribute__((ext_vector_type(4)));

typedef __attribute__((address_space(3))) unsigned int lds_uint;
typedef __attribute__((address_space(1))) const unsigned int glb_uint;
__device__ __forceinline__ void gl_lds16(const void* g, void* l) {
  __builtin_amdgcn_global_load_lds((glb_uint*)g, (lds_uint*)l, 16, 0, 0);
}

// ---------------------------------------------------------------------------
// Mask canonicalization — element-size agnostic (bool byte / int32 / int64).
// ---------------------------------------------------------------------------
__global__ __launch_bounds__(256) void detect_kernel(
    const unsigned char* __restrict__ mask, int* __restrict__ flag,
    int* __restrict__ act) {
  const int tid = threadIdx.x + blockIdx.x * blockDim.x;
  if (tid < NB * NB) act[tid] = 0;
  if (tid == 0) {
    int e;
    if (mask[1] | mask[2] | mask[3]) e = 1;
    else if (mask[4]) e = 4;
    else e = 8;
    flag[0] = e;
  }
}

__device__ inline int mask_at(const unsigned char* m, size_t idx, int esize) {
  if (esize == 1) return m[idx];
  if (esize == 4) return ((const int*)m)[idx] != 0;
  return ((const long long*)m)[idx] != 0;
}

__global__ __launch_bounds__(64) void masknorm_kernel(
    const unsigned char* __restrict__ mask, const int* __restrict__ flag,
    unsigned long long* __restrict__ colmask, int* __restrict__ act) {
  const int row = blockIdx.x * 2 + (threadIdx.x >> 5);
  const int kb = threadIdx.x & 31;
  const int esize = flag[0];
  unsigned long long bm = 0ull;
  const size_t base = (size_t)row * SEQ + (size_t)kb * 64;
#pragma unroll 8
  for (int c = 0; c < 64; c++)
    if (mask_at(mask, base + c, esize)) bm |= (1ull << c);
  colmask[(size_t)row * NB + kb] = bm;
  if (bm) atomicOr(&act[(row >> 6) * NB + kb], 1);
}

// Deterministic compact active-block list per q-block.
__global__ __launch_bounds__(64) void actlist_kernel(
    const int* __restrict__ act, int* __restrict__ list,
    int* __restrict__ actn) {
  const int qi = blockIdx.x, kb = threadIdx.x;
  bool pred = (kb < NB) && (act[qi * NB + kb] != 0);
  unsigned long long m = __ballot(pred);
  if (pred)
    list[qi * NB + __popcll(m & ((1ull << kb) - 1ull))] = kb;
  if (kb == 0) actn[qi] = (int)__popcll(m);
}

// ---------------------------------------------------------------------------
// Weight transpose+convert: W[K][N] fp32 -> WT[N][K] f16.
// ---------------------------------------------------------------------------
__global__ __launch_bounds__(256) void wtrans_kernel(
    const float* __restrict__ W0, const float* __restrict__ W1,
    const float* __restrict__ W2, const float* __restrict__ W3,
    f16* __restrict__ WT) {
  const float* W = (blockIdx.z == 0) ? W0
                 : (blockIdx.z == 1) ? W1
                 : (blockIdx.z == 2) ? W2 : W3;
  f16* out = WT + (size_t)blockIdx.z * HID * HID;
  __shared__ float T[64][65];
  const int t = threadIdx.x;
  const int k0 = blockIdx.y * 64, n0 = blockIdx.x * 64;
#pragma unroll
  for (int i = 0; i < 4; i++) {
    int f = t + i * 256;
    int kr = f >> 4, nc = (f & 15) << 2;
    float4 v = *(const float4*)(W + (size_t)(k0 + kr) * HID + n0 + nc);
    T[kr][nc] = v.x; T[kr][nc + 1] = v.y; T[kr][nc + 2] = v.z; T[kr][nc + 3] = v.w;
  }
  __syncthreads();
#pragma unroll
  for (int i = 0; i < 4; i++) {
    int f = t + i * 256;
    int nr = f >> 4, kc = (f & 15) << 2;
    f16x4 ov = {(f16)T[kc][nr], (f16)T[kc + 1][nr], (f16)T[kc + 2][nr],
                (f16)T[kc + 3][nr]};
    *(f16x4*)(out + (size_t)(n0 + nr) * HID + k0 + kc) = ov;
  }
}

__global__ __launch_bounds__(256) void xconv_kernel(const float* __restrict__ X,
                                                    f16* __restrict__ Xh) {
  const size_t i = ((size_t)blockIdx.x * 256 + threadIdx.x) * 8;
  float4 a = *(const float4*)(X + i);
  float4 b = *(const float4*)(X + i + 4);
  f16x8 h = {(f16)a.x, (f16)a.y, (f16)a.z, (f16)a.w,
             (f16)b.x, (f16)b.y, (f16)b.z, (f16)b.w};
  *(f16x8*)(Xh + i) = h;
}

// V slice of QKV -> VT[b][h][d][s], LDS-tiled 64x64, coalesced both sides.
__global__ __launch_bounds__(256) void vtrans_kernel(const f16* __restrict__ QKV,
                                                     f16* __restrict__ VT) {
  __shared__ f16 T[64][72];
  const int s0 = blockIdx.x * 64;       // s within batch
  const int d0 = blockIdx.y * 64;       // 0 or 64
  const int bh = blockIdx.z;            // b*16+h
  const int b = bh >> 4, h = bh & 15;
  const int t = threadIdx.x;
  const f16* src = QKV + (size_t)(b * SEQ + s0) * NQKV + 2 * HID + h * DHEAD + d0;
#pragma unroll
  for (int i = 0; i < 2; i++) {
    int f = t + i * 256;
    int sr = f >> 3, c8 = (f & 7) << 3;
    *(f16x8*)(&T[sr][c8]) = *(const f16x8*)(src + (size_t)sr * NQKV + c8);
  }
  __syncthreads();
  f16* dst = VT + ((size_t)bh * DHEAD + d0) * SEQ + s0;
#pragma unroll
  for (int i = 0; i < 2; i++) {
    int f = t + i * 256;
    int dr = f >> 3, c8 = (f & 7) << 3;
    f16x8 ov;
#pragma unroll
    for (int j = 0; j < 8; j++) ov[j] = T[c8 + j][dr];
    *(f16x8*)(dst + (size_t)dr * SEQ + c8) = ov;
  }
}

// ---------------------------------------------------------------------------
// fp16-MFMA GEMM, m97 structure: linear LDS + global_load_lds(16B).
// 256 thr = 4 waves (2x2), tile 128x128, BK=32.
// ---------------------------------------------------------------------------
template <bool C_F16>
__global__ __launch_bounds__(256) void hgemm_kernel(
    const f16* __restrict__ A, const f16* __restrict__ BT,
    void* __restrict__ Cp, int M, int N, int K) {
  __shared__ f16 Ah[128 * 32];
  __shared__ f16 Bh[128 * 32];
  const int tid = threadIdx.x;
  const int m0 = blockIdx.y * 128, n0 = blockIdx.x * 128;
  const int lane = tid & 63, wid = tid >> 6;
  const int wr = (wid >> 1) * 64, wc = (wid & 1) * 64;
  const int fr = lane & 15;
  const int k8 = (lane >> 4) * 8;

  const f16* Asrc = A + (size_t)(m0 + wid * 32 + (lane >> 2)) * K + ((lane & 3) << 3);
  const f16* Bsrc = BT + (size_t)(n0 + wid * 32 + (lane >> 2)) * K + ((lane & 3) << 3);

  f32x4 acc[4][4] = {};

  for (int kk = 0; kk < K; kk += 32) {
    __syncthreads();
#pragma unroll
    for (int i = 0; i < 2; i++) {
      gl_lds16(Asrc + (size_t)(i * 16) * K + kk, &Ah[(wid * 32 + i * 16) * 32]);
      gl_lds16(Bsrc + (size_t)(i * 16) * K + kk, &Bh[(wid * 32 + i * 16) * 32]);
    }
    __syncthreads();

    f16x8 af[4], bf[4];
#pragma unroll
    for (int m = 0; m < 4; m++)
      af[m] = *(const f16x8*)(&Ah[(wr + m * 16 + fr) * 32 + k8]);
#pragma unroll
    for (int n = 0; n < 4; n++)
      bf[n] = *(const f16x8*)(&Bh[(wc + n * 16 + fr) * 32 + k8]);
#pragma unroll
    for (int m = 0; m < 4; m++)
#pragma unroll
      for (int n = 0; n < 4; n++)
        acc[m][n] = __builtin_amdgcn_mfma_f32_16x16x32_f16(af[m], bf[n],
                                                           acc[m][n], 0, 0, 0);
  }

  const int crow = (lane >> 4) * 4;
#pragma unroll
  for (int m = 0; m < 4; m++)
#pragma unroll
    for (int n = 0; n < 4; n++) {
      int gr = m0 + wr + m * 16 + crow;
      int gc = n0 + wc + n * 16 + fr;
#pragma unroll
      for (int j = 0; j < 4; j++) {
        if (C_F16)
          ((f16*)Cp)[(size_t)(gr + j) * N + gc] = (f16)acc[m][n][j];
        else
          ((float*)Cp)[(size_t)(gr + j) * N + gc] = acc[m][n][j];
      }
    }
}

// ---------------------------------------------------------------------------
// MFMA block-sparse flash attention, double-buffered async staging.
// 1D grid 1024 = (qi, h, b) XCD-swizzled so all qi of one (h,b) share an XCD.
// K staged [64][128] f16, V^T staged [128][64] f16 — both linear LDS via
// global_load_lds with pre-swizzled source cols (col ^= 8*(row&7)); frag
// reads apply the same XOR (bank-uniform, conflict-free).
// One barrier per iteration: barrier -> issue next tile (async) -> compute.
// ---------------------------------------------------------------------------
__global__ __launch_bounds__(256) void attn_kernel(
    const f16* __restrict__ Q, const f16* __restrict__ K,
    const f16* __restrict__ VT, const unsigned long long* __restrict__ colmask,
    const int* __restrict__ list, const int* __restrict__ actn,
    f16* __restrict__ AO, int ldq) {
  const int wgid = blockIdx.x;
  const int xcd = wgid & 7, idx = wgid >> 3;
  const int qi = idx & 31;
  const int hb = xcd + ((idx >> 5) << 3);
  const int h = hb & 15, b = hb >> 4;

  const int tid = threadIdx.x;
  const int lane = tid & 63, w = tid >> 6;
  const int l15 = lane & 15, l4 = lane >> 4;
  const float SCALE = 0.08838834764831845f;

  __shared__ f16 KT2[2][64 * 128];    // 32 KB
  __shared__ f16 VT2[2][128 * 64];    // 32 KB
  __shared__ f16 Ps[4][16 * 72];      // 9 KB
  __shared__ float Cs[4][16];
  __shared__ float Ls[4][16];

  const f16* Kbase = K + (size_t)(b * SEQ) * ldq + h * DHEAD;
  const f16* Vbase = VT + (size_t)hb * DHEAD * SEQ;

  // Q fragments: row = w*16 + l15, k-chunks of 32 d.
  const f16* Qp = Q + (size_t)(b * SEQ + qi * 64 + w * 16 + l15) * ldq + h * DHEAD;
  f16x8 qf[4];
#pragma unroll
  for (int kc = 0; kc < 4; kc++)
    qf[kc] = *(const f16x8*)(Qp + kc * 32 + l4 * 8);

  const unsigned long long* cmbase =
      colmask + (size_t)(qi * 64 + w * 16 + l4 * 4) * NB;

  float mrow[4], lrow[4];
#pragma unroll
  for (int j = 0; j < 4; j++) { mrow[j] = -3.0e38f; lrow[j] = 0.f; }
  f32x4 oacc[8] = {};

  const int nact = actn[qi];
  const int* lst = list + qi * NB;

  // async stage of tile kb into buffer buf (wave w's share)
  auto issue_tile = [&](int buf, int kb) {
    const f16* Kp = Kbase + (size_t)(kb * 64) * ldq;
    const f16* Vp = Vbase + kb * 64;
#pragma unroll
    for (int i = 0; i < 4; i++) {
      int r = w * 16 + i * 4 + l4;                    // K row 0..63
      int c = (l15 << 3) ^ ((r & 7) << 3);            // pre-swizzled col
      gl_lds16(Kp + (size_t)r * ldq + c, &KT2[buf][(w * 16 + i * 4) * 128]);
      int d = w * 32 + i * 8 + (lane >> 3);           // VT row 0..127
      int c2 = ((lane & 7) << 3) ^ ((d & 7) << 3);
      gl_lds16(Vp + (size_t)d * SEQ + c2, &VT2[buf][(w * 32 + i * 8) * 64]);
    }
  };

  if (nact > 0) issue_tile(0, lst[0]);

  for (int it = 0; it < nact; it++) {
    const int kb = lst[it];
    const int cur = it & 1;
    __syncthreads();   // drains async loads for buf[cur]; frees buf[cur^1]
    if (it + 1 < nact) issue_tile(cur ^ 1, lst[it + 1]);

    // ---- QK^T ----
    f32x4 sacc[4] = {};
    __builtin_amdgcn_s_setprio(1);
#pragma unroll
    for (int t = 0; t < 4; t++) {
      const int kr = t * 16 + l15;
#pragma unroll
      for (int kc = 0; kc < 4; kc++) {
        f16x8 kf = *(const f16x8*)(&KT2[cur][kr * 128 +
                        ((kc * 32 + l4 * 8) ^ ((l15 & 7) << 3))]);
        sacc[t] =
            __builtin_amdgcn_mfma_f32_16x16x32_f16(qf[kc], kf, sacc[t], 0, 0, 0);
      }
    }
    __builtin_amdgcn_s_setprio(0);

    // ---- mask + online softmax (state rows q = w*16 + l4*4 + j) ----
    unsigned long long cm[4];
#pragma unroll
    for (int j = 0; j < 4; j++) cm[j] = cmbase[j * NB + kb];

    float bmax[4] = {-3.0e38f, -3.0e38f, -3.0e38f, -3.0e38f};
    float sc[4][4];
#pragma unroll
    for (int t = 0; t < 4; t++)
#pragma unroll
      for (int j = 0; j < 4; j++) {
        float sv = sacc[t][j] * SCALE;
        if (!((cm[j] >> (t * 16 + l15)) & 1ull)) sv = -3.0e38f;
        sc[t][j] = sv;
        bmax[j] = fmaxf(bmax[j], sv);
      }
#pragma unroll
    for (int j = 0; j < 4; j++) {
      bmax[j] = fmaxf(bmax[j], __shfl_xor(bmax[j], 1));
      bmax[j] = fmaxf(bmax[j], __shfl_xor(bmax[j], 2));
      bmax[j] = fmaxf(bmax[j], __shfl_xor(bmax[j], 4));
      bmax[j] = fmaxf(bmax[j], __shfl_xor(bmax[j], 8));
    }
    float co[4], psum[4] = {0.f, 0.f, 0.f, 0.f};
#pragma unroll
    for (int j = 0; j < 4; j++) {
      float mnew = fmaxf(mrow[j], bmax[j]);
      co[j] = __expf(mrow[j] - mnew);
      mrow[j] = mnew;
    }
#pragma unroll
    for (int t = 0; t < 4; t++)
#pragma unroll
      for (int j = 0; j < 4; j++) {
        float p = __expf(sc[t][j] - mrow[j]);
        psum[j] += p;
        Ps[w][(l4 * 4 + j) * 72 + t * 16 + l15] = (f16)p;
      }
#pragma unroll
    for (int j = 0; j < 4; j++) {
      psum[j] += __shfl_xor(psum[j], 1);
      psum[j] += __shfl_xor(psum[j], 2);
      psum[j] += __shfl_xor(psum[j], 4);
      psum[j] += __shfl_xor(psum[j], 8);
      lrow[j] = lrow[j] * co[j] + psum[j];
    }
    if (l15 == 0) {
#pragma unroll
      for (int j = 0; j < 4; j++) Cs[w][l4 * 4 + j] = co[j];
    }
    asm volatile("s_waitcnt lgkmcnt(0)" ::: "memory");
    __builtin_amdgcn_sched_barrier(0);

    // ---- rescale O^T by co(q = l15), then PV ----
    float cq = Cs[w][l15];
#pragma unroll
    for (int dt = 0; dt < 8; dt++)
#pragma unroll
      for (int j = 0; j < 4; j++) oacc[dt][j] *= cq;

    f16x8 pf[2];
#pragma unroll
    for (int kc = 0; kc < 2; kc++)
      pf[kc] = *(const f16x8*)(&Ps[w][l15 * 72 + kc * 32 + l4 * 8]);
    __builtin_amdgcn_s_setprio(1);
#pragma unroll
    for (int dt = 0; dt < 8; dt++) {
      const int d = dt * 16 + l15;
#pragma unroll
      for (int kc = 0; kc < 2; kc++) {
        f16x8 vf = *(const f16x8*)(&VT2[cur][d * 64 +
                        ((kc * 32 + l4 * 8) ^ ((l15 & 7) << 3))]);
        oacc[dt] =
            __builtin_amdgcn_mfma_f32_16x16x32_f16(vf, pf[kc], oacc[dt], 0, 0, 0);
      }
    }
    __builtin_amdgcn_s_setprio(0);
  }

  // ---- epilogue ----
  if (l15 == 0) {
#pragma unroll
    for (int j = 0; j < 4; j++) Ls[w][l4 * 4 + j] = lrow[j];
  }
  asm volatile("s_waitcnt lgkmcnt(0)" ::: "memory");
  __builtin_amdgcn_sched_barrier(0);
  const float linv = 1.0f / Ls[w][l15];
  f16* Op = AO + (size_t)(b * SEQ + qi * 64 + w * 16 + l15) * HID + h * DHEAD;
#pragma unroll
  for (int dt = 0; dt < 8; dt++) {
    f16x4 ov = {(f16)(oacc[dt][0] * linv), (f16)(oacc[dt][1] * linv),
                (f16)(oacc[dt][2] * linv), (f16)(oacc[dt][3] * linv)};
    *(f16x4*)(Op + dt * 16 + l4 * 4) = ov;
  }
}

// ---------------------------------------------------------------------------
extern "C" void kernel_launch(void* const* d_in, const int* in_sizes, int n_in,
                              void* d_out, int out_size, void* d_ws,
                              size_t ws_size, hipStream_t stream) {
  const float* X  = (const float*)d_in[0];
  const float* Wq = (const float*)d_in[1];
  const float* Wk = (const float*)d_in[2];
  const float* Wv = (const float*)d_in[3];
  const float* Wo = (const float*)d_in[4];
  const unsigned char* mask = (const unsigned char*)d_in[5];
  float* out = (float*)d_out;

  // ws layout (~128.5 MB)
  f16* WT  = (f16*)d_ws;                               // 32 MB
  f16* Xh  = WT + (size_t)4 * HID * HID;               // 16 MB
  f16* QKV = Xh + (size_t)MROWS * HID;                 // 48 MB
  f16* VTb = QKV + (size_t)MROWS * NQKV;               // 16 MB
  f16* AOh = VTb + (size_t)MROWS * HID;                // 16 MB
  unsigned long long* colmask =
      (unsigned long long*)(AOh + (size_t)MROWS * HID);  // 512 KB
  int* act  = (int*)(colmask + (size_t)SEQ * NB);
  int* list = act + NB * NB;
  int* actn = list + NB * NB;
  int* flag = actn + NB;

  detect_kernel<<<4, 256, 0, stream>>>(mask, flag, act);
  masknorm_kernel<<<SEQ / 2, 64, 0, stream>>>(mask, flag, colmask, act);
  actlist_kernel<<<NB, 64, 0, stream>>>(act, list, actn);
  wtrans_kernel<<<dim3(HID / 64, HID / 64, 4), 256, 0, stream>>>(Wq, Wk, Wv,
                                                                 Wo, WT);
  xconv_kernel<<<(MROWS * HID) / (256 * 8), 256, 0, stream>>>(X, Xh);

  hgemm_kernel<true><<<dim3(NQKV / 128, MROWS / 128), 256, 0, stream>>>(
      Xh, WT, QKV, MROWS, NQKV, HID);

  vtrans_kernel<<<dim3(SEQ / 64, DHEAD / 64, BATCH * NHEAD), 256, 0, stream>>>(
      QKV, VTb);

  attn_kernel<<<NB * NHEAD * BATCH, 256, 0, stream>>>(
      QKV, QKV + HID, VTb, colmask, list, actn, AOh, NQKV);

  hgemm_kernel<false><<<dim3(HID / 128, MROWS / 128), 256, 0, stream>>>(
      AOh, WT + (size_t)3 * HID * HID, out, MROWS, HID, HID);
}

// Round 10
// 446.681 us; speedup vs baseline: 4.0889x; 1.0750x over previous
//
#include <hip/hip_runtime.h>
#include <hip/hip_bf16.h>
#include <math.h>

#define SEQ   2048
#define HID   2048
#define NHEAD 16
#define DHEAD 128
#define NB    32
#define BATCH 2
#define MROWS (BATCH * SEQ)   // 4096
#define NQKV  (3 * HID)       // 6144

typedef _Float16 f16;
typedef _Float16 f16x8 __attribute__((ext_vector_type(8)));
typedef _Float16 f16x4 __attribute__((ext_vector_type(4)));
typedef float f32x4 __attribute__((ext_vector_type(4)));

typedef __attribute__((address_space(3))) unsigned int lds_uint;
typedef __attribute__((address_space(1))) const unsigned int glb_uint;
__device__ __forceinline__ void gl_lds16(const void* g, void* l) {
  __builtin_amdgcn_global_load_lds((glb_uint*)g, (lds_uint*)l, 16, 0, 0);
}

// ---------------------------------------------------------------------------
// Mask canonicalization — element-size agnostic (bool byte / int32 / int64).
// ---------------------------------------------------------------------------
__global__ __launch_bounds__(256) void detect_kernel(
    const unsigned char* __restrict__ mask, int* __restrict__ flag,
    int* __restrict__ act) {
  const int tid = threadIdx.x + blockIdx.x * blockDim.x;
  if (tid < NB * NB) act[tid] = 0;
  if (tid == 0) {
    int e;
    if (mask[1] | mask[2] | mask[3]) e = 1;
    else if (mask[4]) e = 4;
    else e = 8;
    flag[0] = e;
  }
}

__device__ inline int mask_at(const unsigned char* m, size_t idx, int esize) {
  if (esize == 1) return m[idx];
  if (esize == 4) return ((const int*)m)[idx] != 0;
  return ((const long long*)m)[idx] != 0;
}

__global__ __launch_bounds__(64) void masknorm_kernel(
    const unsigned char* __restrict__ mask, const int* __restrict__ flag,
    unsigned long long* __restrict__ colmask, int* __restrict__ act) {
  const int row = blockIdx.x * 2 + (threadIdx.x >> 5);
  const int kb = threadIdx.x & 31;
  const int esize = flag[0];
  unsigned long long bm = 0ull;
  const size_t base = (size_t)row * SEQ + (size_t)kb * 64;
#pragma unroll 8
  for (int c = 0; c < 64; c++)
    if (mask_at(mask, base + c, esize)) bm |= (1ull << c);
  colmask[(size_t)row * NB + kb] = bm;
  if (bm) atomicOr(&act[(row >> 6) * NB + kb], 1);
}

// Deterministic compact active-block list per q-block.
__global__ __launch_bounds__(64) void actlist_kernel(
    const int* __restrict__ act, int* __restrict__ list,
    int* __restrict__ actn) {
  const int qi = blockIdx.x, kb = threadIdx.x;
  bool pred = (kb < NB) && (act[qi * NB + kb] != 0);
  unsigned long long m = __ballot(pred);
  if (pred)
    list[qi * NB + __popcll(m & ((1ull << kb) - 1ull))] = kb;
  if (kb == 0) actn[qi] = (int)__popcll(m);
}

// ---------------------------------------------------------------------------
// Weight transpose+convert: W[K][N] fp32 -> WT[N][K] f16.
// ---------------------------------------------------------------------------
__global__ __launch_bounds__(256) void wtrans_kernel(
    const float* __restrict__ W0, const float* __restrict__ W1,
    const float* __restrict__ W2, const float* __restrict__ W3,
    f16* __restrict__ WT) {
  const float* W = (blockIdx.z == 0) ? W0
                 : (blockIdx.z == 1) ? W1
                 : (blockIdx.z == 2) ? W2 : W3;
  f16* out = WT + (size_t)blockIdx.z * HID * HID;
  __shared__ float T[64][65];
  const int t = threadIdx.x;
  const int k0 = blockIdx.y * 64, n0 = blockIdx.x * 64;
#pragma unroll
  for (int i = 0; i < 4; i++) {
    int f = t + i * 256;
    int kr = f >> 4, nc = (f & 15) << 2;
    float4 v = *(const float4*)(W + (size_t)(k0 + kr) * HID + n0 + nc);
    T[kr][nc] = v.x; T[kr][nc + 1] = v.y; T[kr][nc + 2] = v.z; T[kr][nc + 3] = v.w;
  }
  __syncthreads();
#pragma unroll
  for (int i = 0; i < 4; i++) {
    int f = t + i * 256;
    int nr = f >> 4, kc = (f & 15) << 2;
    f16x4 ov = {(f16)T[kc][nr], (f16)T[kc + 1][nr], (f16)T[kc + 2][nr],
                (f16)T[kc + 3][nr]};
    *(f16x4*)(out + (size_t)(n0 + nr) * HID + k0 + kc) = ov;
  }
}

__global__ __launch_bounds__(256) void xconv_kernel(const float* __restrict__ X,
                                                    f16* __restrict__ Xh) {
  const size_t i = ((size_t)blockIdx.x * 256 + threadIdx.x) * 8;
  float4 a = *(const float4*)(X + i);
  float4 b = *(const float4*)(X + i + 4);
  f16x8 h = {(f16)a.x, (f16)a.y, (f16)a.z, (f16)a.w,
             (f16)b.x, (f16)b.y, (f16)b.z, (f16)b.w};
  *(f16x8*)(Xh + i) = h;
}

// V slice of QKV -> VT[b][h][d][s], LDS-tiled 64x64, coalesced both sides.
__global__ __launch_bounds__(256) void vtrans_kernel(const f16* __restrict__ QKV,
                                                     f16* __restrict__ VT) {
  __shared__ f16 T[64][72];
  const int s0 = blockIdx.x * 64;       // s within batch
  const int d0 = blockIdx.y * 64;       // 0 or 64
  const int bh = blockIdx.z;            // b*16+h
  const int b = bh >> 4, h = bh & 15;
  const int t = threadIdx.x;
  const f16* src = QKV + (size_t)(b * SEQ + s0) * NQKV + 2 * HID + h * DHEAD + d0;
#pragma unroll
  for (int i = 0; i < 2; i++) {
    int f = t + i * 256;
    int sr = f >> 3, c8 = (f & 7) << 3;
    *(f16x8*)(&T[sr][c8]) = *(const f16x8*)(src + (size_t)sr * NQKV + c8);
  }
  __syncthreads();
  f16* dst = VT + ((size_t)bh * DHEAD + d0) * SEQ + s0;
#pragma unroll
  for (int i = 0; i < 2; i++) {
    int f = t + i * 256;
    int dr = f >> 3, c8 = (f & 7) << 3;
    f16x8 ov;
#pragma unroll
    for (int j = 0; j < 8; j++) ov[j] = T[c8 + j][dr];
    *(f16x8*)(dst + (size_t)dr * SEQ + c8) = ov;
  }
}

// ---------------------------------------------------------------------------
// fp16-MFMA GEMM, double-buffered T3-min pipeline:
//   prologue: STAGE(buf0, 0)
//   per K-step: sync (drains buf[cur] loads) -> STAGE(buf[cur^1], next)
//               -> ds_read frags(buf[cur]) -> 16 MFMA -> cur^=1
// Stage latency hides under the compute phase; one barrier per K-step.
// 256 thr = 4 waves (2x2), tile 128x128, BK=32, linear LDS + gl_lds16(16B).
// ---------------------------------------------------------------------------
template <bool C_F16>
__global__ __launch_bounds__(256) void hgemm_kernel(
    const f16* __restrict__ A, const f16* __restrict__ BT,
    void* __restrict__ Cp, int M, int N, int K) {
  __shared__ f16 Ah[2][128 * 32];
  __shared__ f16 Bh[2][128 * 32];
  const int tid = threadIdx.x;
  const int m0 = blockIdx.y * 128, n0 = blockIdx.x * 128;
  const int lane = tid & 63, wid = tid >> 6;
  const int wr = (wid >> 1) * 64, wc = (wid & 1) * 64;
  const int fr = lane & 15;
  const int k8 = (lane >> 4) * 8;

  const f16* Asrc = A + (size_t)(m0 + wid * 32 + (lane >> 2)) * K + ((lane & 3) << 3);
  const f16* Bsrc = BT + (size_t)(n0 + wid * 32 + (lane >> 2)) * K + ((lane & 3) << 3);

  f32x4 acc[4][4] = {};

  auto stage = [&](int buf, int kk) {
#pragma unroll
    for (int i = 0; i < 2; i++) {
      gl_lds16(Asrc + (size_t)(i * 16) * K + kk,
               &Ah[buf][(wid * 32 + i * 16) * 32]);
      gl_lds16(Bsrc + (size_t)(i * 16) * K + kk,
               &Bh[buf][(wid * 32 + i * 16) * 32]);
    }
  };

  stage(0, 0);
  int cur = 0;

  for (int kk = 0; kk < K; kk += 32) {
    __syncthreads();                      // buf[cur] staged; buf[cur^1] free
    if (kk + 32 < K) stage(cur ^ 1, kk + 32);

    f16x8 af[4], bf[4];
#pragma unroll
    for (int m = 0; m < 4; m++)
      af[m] = *(const f16x8*)(&Ah[cur][(wr + m * 16 + fr) * 32 + k8]);
#pragma unroll
    for (int n = 0; n < 4; n++)
      bf[n] = *(const f16x8*)(&Bh[cur][(wc + n * 16 + fr) * 32 + k8]);
#pragma unroll
    for (int m = 0; m < 4; m++)
#pragma unroll
      for (int n = 0; n < 4; n++)
        acc[m][n] = __builtin_amdgcn_mfma_f32_16x16x32_f16(af[m], bf[n],
                                                           acc[m][n], 0, 0, 0);
    cur ^= 1;
  }

  const int crow = (lane >> 4) * 4;
#pragma unroll
  for (int m = 0; m < 4; m++)
#pragma unroll
    for (int n = 0; n < 4; n++) {
      int gr = m0 + wr + m * 16 + crow;
      int gc = n0 + wc + n * 16 + fr;
#pragma unroll
      for (int j = 0; j < 4; j++) {
        if (C_F16)
          ((f16*)Cp)[(size_t)(gr + j) * N + gc] = (f16)acc[m][n][j];
        else
          ((float*)Cp)[(size_t)(gr + j) * N + gc] = acc[m][n][j];
      }
    }
}

// ---------------------------------------------------------------------------
// MFMA block-sparse flash attention, double-buffered async staging.
// (unchanged from round 8 — validated)
// ---------------------------------------------------------------------------
__global__ __launch_bounds__(256) void attn_kernel(
    const f16* __restrict__ Q, const f16* __restrict__ K,
    const f16* __restrict__ VT, const unsigned long long* __restrict__ colmask,
    const int* __restrict__ list, const int* __restrict__ actn,
    f16* __restrict__ AO, int ldq) {
  const int wgid = blockIdx.x;
  const int xcd = wgid & 7, idx = wgid >> 3;
  const int qi = idx & 31;
  const int hb = xcd + ((idx >> 5) << 3);
  const int h = hb & 15, b = hb >> 4;

  const int tid = threadIdx.x;
  const int lane = tid & 63, w = tid >> 6;
  const int l15 = lane & 15, l4 = lane >> 4;
  const float SCALE = 0.08838834764831845f;

  __shared__ f16 KT2[2][64 * 128];    // 32 KB
  __shared__ f16 VT2[2][128 * 64];    // 32 KB
  __shared__ f16 Ps[4][16 * 72];      // 9 KB
  __shared__ float Cs[4][16];
  __shared__ float Ls[4][16];

  const f16* Kbase = K + (size_t)(b * SEQ) * ldq + h * DHEAD;
  const f16* Vbase = VT + (size_t)hb * DHEAD * SEQ;

  // Q fragments: row = w*16 + l15, k-chunks of 32 d.
  const f16* Qp = Q + (size_t)(b * SEQ + qi * 64 + w * 16 + l15) * ldq + h * DHEAD;
  f16x8 qf[4];
#pragma unroll
  for (int kc = 0; kc < 4; kc++)
    qf[kc] = *(const f16x8*)(Qp + kc * 32 + l4 * 8);

  const unsigned long long* cmbase =
      colmask + (size_t)(qi * 64 + w * 16 + l4 * 4) * NB;

  float mrow[4], lrow[4];
#pragma unroll
  for (int j = 0; j < 4; j++) { mrow[j] = -3.0e38f; lrow[j] = 0.f; }
  f32x4 oacc[8] = {};

  const int nact = actn[qi];
  const int* lst = list + qi * NB;

  // async stage of tile kb into buffer buf (wave w's share)
  auto issue_tile = [&](int buf, int kb) {
    const f16* Kp = Kbase + (size_t)(kb * 64) * ldq;
    const f16* Vp = Vbase + kb * 64;
#pragma unroll
    for (int i = 0; i < 4; i++) {
      int r = w * 16 + i * 4 + l4;                    // K row 0..63
      int c = (l15 << 3) ^ ((r & 7) << 3);            // pre-swizzled col
      gl_lds16(Kp + (size_t)r * ldq + c, &KT2[buf][(w * 16 + i * 4) * 128]);
      int d = w * 32 + i * 8 + (lane >> 3);           // VT row 0..127
      int c2 = ((lane & 7) << 3) ^ ((d & 7) << 3);
      gl_lds16(Vp + (size_t)d * SEQ + c2, &VT2[buf][(w * 32 + i * 8) * 64]);
    }
  };

  if (nact > 0) issue_tile(0, lst[0]);

  for (int it = 0; it < nact; it++) {
    const int kb = lst[it];
    const int cur = it & 1;
    __syncthreads();   // drains async loads for buf[cur]; frees buf[cur^1]
    if (it + 1 < nact) issue_tile(cur ^ 1, lst[it + 1]);

    // ---- QK^T ----
    f32x4 sacc[4] = {};
    __builtin_amdgcn_s_setprio(1);
#pragma unroll
    for (int t = 0; t < 4; t++) {
      const int kr = t * 16 + l15;
#pragma unroll
      for (int kc = 0; kc < 4; kc++) {
        f16x8 kf = *(const f16x8*)(&KT2[cur][kr * 128 +
                        ((kc * 32 + l4 * 8) ^ ((l15 & 7) << 3))]);
        sacc[t] =
            __builtin_amdgcn_mfma_f32_16x16x32_f16(qf[kc], kf, sacc[t], 0, 0, 0);
      }
    }
    __builtin_amdgcn_s_setprio(0);

    // ---- mask + online softmax (state rows q = w*16 + l4*4 + j) ----
    unsigned long long cm[4];
#pragma unroll
    for (int j = 0; j < 4; j++) cm[j] = cmbase[j * NB + kb];

    float bmax[4] = {-3.0e38f, -3.0e38f, -3.0e38f, -3.0e38f};
    float sc[4][4];
#pragma unroll
    for (int t = 0; t < 4; t++)
#pragma unroll
      for (int j = 0; j < 4; j++) {
        float sv = sacc[t][j] * SCALE;
        if (!((cm[j] >> (t * 16 + l15)) & 1ull)) sv = -3.0e38f;
        sc[t][j] = sv;
        bmax[j] = fmaxf(bmax[j], sv);
      }
#pragma unroll
    for (int j = 0; j < 4; j++) {
      bmax[j] = fmaxf(bmax[j], __shfl_xor(bmax[j], 1));
      bmax[j] = fmaxf(bmax[j], __shfl_xor(bmax[j], 2));
      bmax[j] = fmaxf(bmax[j], __shfl_xor(bmax[j], 4));
      bmax[j] = fmaxf(bmax[j], __shfl_xor(bmax[j], 8));
    }
    float co[4], psum[4] = {0.f, 0.f, 0.f, 0.f};
#pragma unroll
    for (int j = 0; j < 4; j++) {
      float mnew = fmaxf(mrow[j], bmax[j]);
      co[j] = __expf(mrow[j] - mnew);
      mrow[j] = mnew;
    }
#pragma unroll
    for (int t = 0; t < 4; t++)
#pragma unroll
      for (int j = 0; j < 4; j++) {
        float p = __expf(sc[t][j] - mrow[j]);
        psum[j] += p;
        Ps[w][(l4 * 4 + j) * 72 + t * 16 + l15] = (f16)p;
      }
#pragma unroll
    for (int j = 0; j < 4; j++) {
      psum[j] += __shfl_xor(psum[j], 1);
      psum[j] += __shfl_xor(psum[j], 2);
      psum[j] += __shfl_xor(psum[j], 4);
      psum[j] += __shfl_xor(psum[j], 8);
      lrow[j] = lrow[j] * co[j] + psum[j];
    }
    if (l15 == 0) {
#pragma unroll
      for (int j = 0; j < 4; j++) Cs[w][l4 * 4 + j] = co[j];
    }
    asm volatile("s_waitcnt lgkmcnt(0)" ::: "memory");
    __builtin_amdgcn_sched_barrier(0);

    // ---- rescale O^T by co(q = l15), then PV ----
    float cq = Cs[w][l15];
#pragma unroll
    for (int dt = 0; dt < 8; dt++)
#pragma unroll
      for (int j = 0; j < 4; j++) oacc[dt][j] *= cq;

    f16x8 pf[2];
#pragma unroll
    for (int kc = 0; kc < 2; kc++)
      pf[kc] = *(const f16x8*)(&Ps[w][l15 * 72 + kc * 32 + l4 * 8]);
    __builtin_amdgcn_s_setprio(1);
#pragma unroll
    for (int dt = 0; dt < 8; dt++) {
      const int d = dt * 16 + l15;
#pragma unroll
      for (int kc = 0; kc < 2; kc++) {
        f16x8 vf = *(const f16x8*)(&VT2[cur][d * 64 +
                        ((kc * 32 + l4 * 8) ^ ((l15 & 7) << 3))]);
        oacc[dt] =
            __builtin_amdgcn_mfma_f32_16x16x32_f16(vf, pf[kc], oacc[dt], 0, 0, 0);
      }
    }
    __builtin_amdgcn_s_setprio(0);
  }

  // ---- epilogue ----
  if (l15 == 0) {
#pragma unroll
    for (int j = 0; j < 4; j++) Ls[w][l4 * 4 + j] = lrow[j];
  }
  asm volatile("s_waitcnt lgkmcnt(0)" ::: "memory");
  __builtin_amdgcn_sched_barrier(0);
  const float linv = 1.0f / Ls[w][l15];
  f16* Op = AO + (size_t)(b * SEQ + qi * 64 + w * 16 + l15) * HID + h * DHEAD;
#pragma unroll
  for (int dt = 0; dt < 8; dt++) {
    f16x4 ov = {(f16)(oacc[dt][0] * linv), (f16)(oacc[dt][1] * linv),
                (f16)(oacc[dt][2] * linv), (f16)(oacc[dt][3] * linv)};
    *(f16x4*)(Op + dt * 16 + l4 * 4) = ov;
  }
}

// ---------------------------------------------------------------------------
extern "C" void kernel_launch(void* const* d_in, const int* in_sizes, int n_in,
                              void* d_out, int out_size, void* d_ws,
                              size_t ws_size, hipStream_t stream) {
  const float* X  = (const float*)d_in[0];
  const float* Wq = (const float*)d_in[1];
  const float* Wk = (const float*)d_in[2];
  const float* Wv = (const float*)d_in[3];
  const float* Wo = (const float*)d_in[4];
  const unsigned char* mask = (const unsigned char*)d_in[5];
  float* out = (float*)d_out;

  // ws layout (~128.5 MB)
  f16* WT  = (f16*)d_ws;                               // 32 MB
  f16* Xh  = WT + (size_t)4 * HID * HID;               // 16 MB
  f16* QKV = Xh + (size_t)MROWS * HID;                 // 48 MB
  f16* VTb = QKV + (size_t)MROWS * NQKV;               // 16 MB
  f16* AOh = VTb + (size_t)MROWS * HID;                // 16 MB
  unsigned long long* colmask =
      (unsigned long long*)(AOh + (size_t)MROWS * HID);  // 512 KB
  int* act  = (int*)(colmask + (size_t)SEQ * NB);
  int* list = act + NB * NB;
  int* actn = list + NB * NB;
  int* flag = actn + NB;

  detect_kernel<<<4, 256, 0, stream>>>(mask, flag, act);
  masknorm_kernel<<<SEQ / 2, 64, 0, stream>>>(mask, flag, colmask, act);
  actlist_kernel<<<NB, 64, 0, stream>>>(act, list, actn);
  wtrans_kernel<<<dim3(HID / 64, HID / 64, 4), 256, 0, stream>>>(Wq, Wk, Wv,
                                                                 Wo, WT);
  xconv_kernel<<<(MROWS * HID) / (256 * 8), 256, 0, stream>>>(X, Xh);

  hgemm_kernel<true><<<dim3(NQKV / 128, MROWS / 128), 256, 0, stream>>>(
      Xh, WT, QKV, MROWS, NQKV, HID);

  vtrans_kernel<<<dim3(SEQ / 64, DHEAD / 64, BATCH * NHEAD), 256, 0, stream>>>(
      QKV, VTb);

  attn_kernel<<<NB * NHEAD * BATCH, 256, 0, stream>>>(
      QKV, QKV + HID, VTb, colmask, list, actn, AOh, NQKV);

  hgemm_kernel<false><<<dim3(HID / 128, MROWS / 128), 256, 0, stream>>>(
      AOh, WT + (size_t)3 * HID * HID, out, MROWS, HID, HID);
}